// Round 7
// baseline (343.095 us; speedup 1.0000x reference)
//
#include <hip/hip_runtime.h>

typedef __bf16 bf16_t;
typedef bf16_t bf16x8 __attribute__((ext_vector_type(8)));
typedef bf16_t bf16x4 __attribute__((ext_vector_type(4)));
typedef float f32x4 __attribute__((ext_vector_type(4)));

#define BATCH 4
#define SEQ 4096
#define EMBED 512
#define MTOT (BATCH * SEQ)
#define NSPLIT 2
#define KT (SEQ / NSPLIT)     // 2048 keys per block
#define BC 32
#define FITERS (KT / BC)      // 64

__device__ float  Lbuf_g[NSPLIT][MTOT];  // per-ksplit row exp-sums (plain stores)
__device__ bf16_t Wbf_g[EMBED * EMBED];  // W pre-converted to bf16

// async global->LDS, 16 B per lane; lds base must be wave-uniform
__device__ __forceinline__ void async_copy16(const bf16_t* g, bf16_t* l) {
    __builtin_amdgcn_global_load_lds(
        (const __attribute__((address_space(1))) unsigned int*)g,
        (__attribute__((address_space(3))) unsigned int*)l, 16, 0, 0);
}

// ---------------------------------------------------------------------------
// Stage 0a: W fp32 -> bf16 once.
// ---------------------------------------------------------------------------
__global__ __launch_bounds__(256) void cvt_w_kernel(const float* __restrict__ W) {
    const int i = (blockIdx.x * 256 + threadIdx.x) * 4;
    float4 v = *(const float4*)&W[i];
    bf16x4 o;
    o[0] = (bf16_t)v.x; o[1] = (bf16_t)v.y; o[2] = (bf16_t)v.z; o[3] = (bf16_t)v.w;
    *(bf16x4*)&Wbf_g[i] = o;
}

// ---------------------------------------------------------------------------
// Stage 0b: abuf = bf16(cos(x + theta)) — A operand precomputed once.
// ---------------------------------------------------------------------------
__global__ __launch_bounds__(256) void cvt_a_kernel(
    const float* __restrict__ x, const float* __restrict__ theta,
    bf16_t* __restrict__ abuf)
{
    const int i = (blockIdx.x * 256 + threadIdx.x) * 8;
    float4 a = *(const float4*)&x[i];
    float4 b = *(const float4*)&x[i + 4];
    const int e0 = i & 63;            // 8-aligned, no wrap within 8 elems
    bf16x8 o;
    o[0] = (bf16_t)__cosf(a.x + theta[e0 + 0]);
    o[1] = (bf16_t)__cosf(a.y + theta[e0 + 1]);
    o[2] = (bf16_t)__cosf(a.z + theta[e0 + 2]);
    o[3] = (bf16_t)__cosf(a.w + theta[e0 + 3]);
    o[4] = (bf16_t)__cosf(b.x + theta[e0 + 4]);
    o[5] = (bf16_t)__cosf(b.y + theta[e0 + 5]);
    o[6] = (bf16_t)__cosf(b.z + theta[e0 + 6]);
    o[7] = (bf16_t)__cosf(b.w + theta[e0 + 7]);
    *(bf16x8*)&abuf[i] = o;
}

// ---------------------------------------------------------------------------
// Stage 1: q = A @ W^T + b (M=16384, N=512, K=512), 128x128xBK64 MFMA GEMM,
// T2 both-sides swizzle. NEW (R7): proper m97-style double-buffered K-loop —
// one barrier per K-step, next tile's DMA issued BEFORE computing the
// current tile (compute covers DMA latency; barrier drain ~free). Epilogue
// bounce buffer Es aliases the staging smem (valid after the last barrier),
// keeping LDS at 64 KB -> 2 blocks/CU.
// ---------------------------------------------------------------------------
__global__ __launch_bounds__(256, 2) void gemm_q_kernel(
    const bf16_t* __restrict__ abuf, const float* __restrict__ bias,
    bf16_t* __restrict__ kperm, bf16_t* __restrict__ qt)
{
    __shared__ alignas(16) bf16_t smem[4 * 8192];  // 64 KB: [buf][As 16KB|Bs 16KB]

    const int t    = threadIdx.x;
    const int lane = t & 63;
    const int wave = t >> 6;
    const int l15  = lane & 15;
    const int quad = lane >> 4;
    const int m0   = (blockIdx.x >> 2) * 128;     // 128 m-tiles
    const int n0   = (blockIdx.x & 3) * 128;      // 4 n-tiles
    const int wm   = wave >> 1;                   // 0..1
    const int wn   = wave & 1;                    // 0..1

    const int drow = lane >> 3;                   // 0..7 (row within 8-row chunk)
    const int dseg = lane & 7;                    // 0..7 (16B segment)
    const int sseg = dseg ^ drow;                 // pre-swizzled source segment

    f32x4 acc[4][4];
#pragma unroll
    for (int mt = 0; mt < 4; ++mt)
#pragma unroll
        for (int nt = 0; nt < 4; ++nt) acc[mt][nt] = (f32x4){0.f, 0.f, 0.f, 0.f};

    // ---- staging helper (wave-uniform LDS base per chunk) ----
    auto stage = [&](int buf, int k0) {
        bf16_t* As = smem + buf * 16384;
        bf16_t* Bs = As + 8192;
#pragma unroll
        for (int j = 0; j < 4; ++j) {
            const int c   = wave * 4 + j;         // chunk 0..15 = rows c*8..c*8+7
            const int row = c * 8 + drow;
            async_copy16(&abuf[(size_t)(m0 + row) * 512 + k0 + sseg * 8], &As[c * 512]);
            async_copy16(&Wbf_g[(size_t)(n0 + row) * 512 + k0 + sseg * 8], &Bs[c * 512]);
        }
    };

    stage(0, 0);
    __syncthreads();            // DMA(0) landed
    int cur = 0;
    for (int kk = 0; kk < 8; ++kk) {
        if (kk + 1 < 8) stage(cur ^ 1, (kk + 1) * 64);   // prefetch next tile
        const bf16_t* As = smem + cur * 16384;
        const bf16_t* Bs = As + 8192;
#pragma unroll
        for (int kh = 0; kh < 2; ++kh) {
            bf16x8 af[4], bfr[4];
#pragma unroll
            for (int i = 0; i < 4; ++i) {
                const int rA = wm * 64 + i * 16 + l15;
                const int rB = wn * 64 + i * 16 + l15;
                const int sg = kh * 4 + quad;
                af[i]  = *(const bf16x8*)&As[rA * 64 + (sg ^ (rA & 7)) * 8];
                bfr[i] = *(const bf16x8*)&Bs[rB * 64 + (sg ^ (rB & 7)) * 8];
            }
#pragma unroll
            for (int mt = 0; mt < 4; ++mt)
#pragma unroll
                for (int nt = 0; nt < 4; ++nt)
                    acc[mt][nt] = __builtin_amdgcn_mfma_f32_16x16x32_bf16(af[mt], bfr[nt], acc[mt][nt], 0, 0, 0);
        }
        __syncthreads();        // drains prefetch DMA (covered by compute); frees cur
        cur ^= 1;
    }

    const int b     = m0 >> 12;          // batch
    const int mloc  = m0 & 4095;         // row base within batch (mult of 128)
    bf16_t* Es = smem;                   // 34 KB bounce, aliases staging bufs

    // ---- pass 1: kperm via LDS bounce ----
#pragma unroll
    for (int nt = 0; nt < 4; ++nt) {
        const int colL = wn * 64 + nt * 16 + l15;
        const float bv = bias[n0 + colL];
        const int kfL = colL >> 5;
        const int inc = ((colL >> 3) & 3) * 128 + (colL & 7);
#pragma unroll
        for (int mt = 0; mt < 4; ++mt) {
            const int rowL0 = wm * 64 + mt * 16 + quad * 4;
            const int c     = (rowL0 >> 5) * 8 + ((rowL0 >> 4) & 1) * 4 + kfL;
            const int base  = c * 512 + inc + (rowL0 & 15) * 8;
#pragma unroll
            for (int r = 0; r < 4; ++r)
                Es[base + r * 8] = (bf16_t)(acc[mt][nt][r] + bv);
        }
    }
    __syncthreads();
    {
        const int tileB = mloc >> 5;
        const int kfB   = n0 >> 5;
#pragma unroll
        for (int p = 0; p < 8; ++p) {
            const int flat = p * 256 + t;          // 0..2047
            const int c2   = flat >> 6;            // chunk 0..31
            const int off  = (flat & 63) * 8;
            const int tile = c2 >> 3;
            const int mh   = (c2 >> 2) & 1;
            const int kfL2 = c2 & 3;
            const size_t dst = (size_t)b * (SEQ * EMBED)
                             + (size_t)(tileB + tile) * 16384
                             + (size_t)(mh * 16 + kfB + kfL2) * 512 + off;
            *(bf16x8*)&kperm[dst] = *(const bf16x8*)&Es[c2 * 512 + off];
        }
    }
    __syncthreads();
    // ---- pass 2: qt via LDS transpose, Es as [colL][136] ----
#pragma unroll
    for (int nt = 0; nt < 4; ++nt) {
        const int colL = wn * 64 + nt * 16 + l15;
        const float bv = bias[n0 + colL];
#pragma unroll
        for (int mt = 0; mt < 4; ++mt) {
            const int rowL0 = wm * 64 + mt * 16 + quad * 4;
#pragma unroll
            for (int r = 0; r < 4; ++r)
                Es[colL * 136 + rowL0 + r] = (bf16_t)(acc[mt][nt][r] + bv);
        }
    }
    __syncthreads();
    {
#pragma unroll
        for (int p = 0; p < 8; ++p) {
            const int flat = p * 256 + t;          // 0..2047
            const int col  = flat >> 4;            // 0..127
            const int sub  = flat & 15;            // 8-row chunk
            *(bf16x8*)&qt[((size_t)(b * 512 + n0 + col) << 12) + mloc + sub * 8]
                = *(const bf16x8*)&Es[col * 136 + sub * 8];
        }
    }
}

// ---------------------------------------------------------------------------
// Stage 2: attention — byte-identical to R6 (240 us proven).
// ---------------------------------------------------------------------------
__global__ __launch_bounds__(256, 2) void flash_kernel(
    const bf16_t* __restrict__ kp, const bf16_t* __restrict__ qt,
    float* __restrict__ out, float* __restrict__ obuf, const int split)
{
    __shared__ alignas(16) bf16_t Ks[2][32 * 512];   // 65536 B, frag-major
    __shared__ alignas(16) bf16_t Ps[2][4 * 512];    //  8192 B, frag-major

    const int t    = threadIdx.x;
    const int lane = t & 63;
    const int wave = t >> 6;
    const int l15  = lane & 15;
    const int quad = lane >> 4;

    // XCD-aware remap: 512 blocks, xcd = L&7 owns one (batch, ksplit) group
    const int L      = blockIdx.x;            // 0..511
    const int g      = L & 7;                 // 0..7
    const int qtile  = L >> 3;                // 0..63
    const int batch  = g >> 1;
    const int ksplit = g & 1;

    const int q0     = qtile * 64;
    const int kbase  = ksplit * KT;
    const int ktile0 = kbase >> 5;            // first 32-key tile index
    const bf16_t* kpb = kp + (size_t)batch * SEQ * EMBED;
    const bf16_t* qtb = qt + (size_t)batch * EMBED * SEQ;

    // stage K-tile 0: 32 frags x 1 KB, 8 per wave, linear DMA
#pragma unroll
    for (int cc = 0; cc < 8; ++cc) {
        const int f = cc * 4 + wave;
        async_copy16(&kpb[(size_t)ktile0 * 16384 + f * 512 + lane * 8],
                     &Ks[0][f * 512]);
    }

    // Q B-frags (wave owns q-rows q0+wave*16..+15), read from frag-major kperm
    bf16x8 bQ[16];
    {
        const size_t qb = (size_t)(qtile * 2 + (wave >> 1)) * 16384
                        + (size_t)(wave & 1) * 16 * 512;
#pragma unroll
        for (int kf = 0; kf < 16; ++kf)
            bQ[kf] = *(const bf16x8*)&kpb[qb + kf * 512 + quad * 128 + l15 * 8];
    }

    f32x4 O[4][8];   // PV e-split: wave owns e-range wave*128 (8 n-tiles x 16)
#pragma unroll
    for (int m = 0; m < 4; ++m)
#pragma unroll
        for (int n = 0; n < 8; ++n) O[m][n] = (f32x4){0.f, 0.f, 0.f, 0.f};
    float lpart = 0.f;

    for (int it = 0; it < FITERS; ++it) {
        const int cbuf = it & 1;
        const int pbuf = cbuf ^ 1;
        __syncthreads();   // DMA K(it) landed; Ps(it-1) visible; Ks[pbuf] reads done
        // ---- V(it-1) global loads FIRST (older in vmcnt queue than DMA) ----
        bf16x8 bv[8];
        if (it) {
            const int kv = kbase + (it - 1) * BC;
#pragma unroll
            for (int n = 0; n < 8; ++n)
                bv[n] = *(const bf16x8*)&qtb[(size_t)(wave * 128 + n * 16 + l15) * 4096
                                             + kv + quad * 8];
        }
        // ---- issue DMA K(it+1) into Ks[pbuf] (drains at next barrier) ----
        if (it + 1 < FITERS) {
#pragma unroll
            for (int cc = 0; cc < 8; ++cc) {
                const int f = cc * 4 + wave;
                async_copy16(&kpb[(size_t)(ktile0 + it + 1) * 16384 + f * 512 + lane * 8],
                             &Ks[pbuf][f * 512]);
            }
        }
        // ---- QK(it): S^T = K * Q^T, A=K frag (seq. lane*16 read), B=Q regs ----
        f32x4 s[2];
#pragma unroll
        for (int kt = 0; kt < 2; ++kt) {
            f32x4 a = (f32x4){0.f, 0.f, 0.f, 0.f};
#pragma unroll
            for (int kf = 0; kf < 16; ++kf) {
                bf16x8 ak = *(const bf16x8*)&Ks[cbuf][(kt * 16 + kf) * 512 + lane * 8];
                a = __builtin_amdgcn_mfma_f32_16x16x32_bf16(ak, bQ[kf], a, 0, 0, 0);
            }
            s[kt] = a;
        }
        // ---- P = exp(s/8): lane holds P[q=wave*16+l15][key=kt*16+quad*4+r] ----
#pragma unroll
        for (int kt = 0; kt < 2; ++kt) {
            bf16x4 pk;
#pragma unroll
            for (int r = 0; r < 4; ++r) {
                bf16_t pb = (bf16_t)__expf(s[kt][r] * 0.125f);
                lpart += (float)pb;
                pk[r] = pb;
            }
            *(bf16x4*)&Ps[cbuf][wave * 512 + (kt * 2 + (quad >> 1)) * 128
                                + l15 * 8 + (quad & 1) * 4] = pk;
        }
        // ---- PV(it-1): A=P frags (seq. lane*16 read), B=bv ----
        if (it) {
            bf16x8 pa[4];
#pragma unroll
            for (int mt = 0; mt < 4; ++mt)
                pa[mt] = *(const bf16x8*)&Ps[pbuf][mt * 512 + lane * 8];
            __builtin_amdgcn_s_setprio(1);
#pragma unroll
            for (int n = 0; n < 8; ++n)
#pragma unroll
                for (int mt = 0; mt < 4; ++mt)
                    O[mt][n] = __builtin_amdgcn_mfma_f32_16x16x32_bf16(pa[mt], bv[n], O[mt][n], 0, 0, 0);
            __builtin_amdgcn_s_setprio(0);
        }
    }
    // ---- final PV(FITERS-1) ----
    __syncthreads();
    {
        const int pbuf = (FITERS - 1) & 1;
        const int kv = kbase + (FITERS - 1) * BC;
        bf16x8 bv[8];
#pragma unroll
        for (int n = 0; n < 8; ++n)
            bv[n] = *(const bf16x8*)&qtb[(size_t)(wave * 128 + n * 16 + l15) * 4096
                                         + kv + quad * 8];
        bf16x8 pa[4];
#pragma unroll
        for (int mt = 0; mt < 4; ++mt)
            pa[mt] = *(const bf16x8*)&Ps[pbuf][mt * 512 + lane * 8];
        __builtin_amdgcn_s_setprio(1);
#pragma unroll
        for (int n = 0; n < 8; ++n)
#pragma unroll
            for (int mt = 0; mt < 4; ++mt)
                O[mt][n] = __builtin_amdgcn_mfma_f32_16x16x32_bf16(pa[mt], bv[n], O[mt][n], 0, 0, 0);
        __builtin_amdgcn_s_setprio(0);
    }

    // ---- row exp-sums: plain store, unique writer per (row, ksplit) ----
    {
        float ls = lpart;
        ls += __shfl_xor(ls, 16);
        ls += __shfl_xor(ls, 32);
        if (quad == 0)
            Lbuf_g[ksplit][batch * SEQ + q0 + wave * 16 + l15] = ls;
    }
    // ---- unnormalized O; D: row=quad*4+r (q-row), col=l15 (e) ----
    if (split) {
        float* ob = obuf + (size_t)ksplit * MTOT * EMBED;
#pragma unroll
        for (int mt = 0; mt < 4; ++mt)
#pragma unroll
            for (int r = 0; r < 4; ++r) {
                const size_t row = (size_t)batch * SEQ + q0 + mt * 16 + quad * 4 + r;
#pragma unroll
                for (int n = 0; n < 8; ++n)
                    __builtin_nontemporal_store(O[mt][n][r],
                        &ob[row * 512 + wave * 128 + n * 16 + l15]);
            }
    } else {
#pragma unroll
        for (int mt = 0; mt < 4; ++mt)
#pragma unroll
            for (int r = 0; r < 4; ++r) {
                const size_t row = (size_t)batch * SEQ + q0 + mt * 16 + quad * 4 + r;
#pragma unroll
                for (int n = 0; n < 8; ++n)
                    atomicAdd(&out[row * 512 + wave * 128 + n * 16 + l15], O[mt][n][r]);
            }
    }
}

// out[row][e] = (split ? obuf0+obuf1 : out)[row][e] / (Lbuf[0][row]+Lbuf[1][row])
__global__ __launch_bounds__(256) void norm_kernel(
    float* __restrict__ out, const float* __restrict__ obuf, const int split)
{
    const int idx = blockIdx.x * 256 + threadIdx.x;   // float4 index
    const int row = idx >> 7;
    float4 v;
    if (split) {
        float4 a = ((const float4*)obuf)[idx];
        float4 b = ((const float4*)(obuf + (size_t)MTOT * EMBED))[idx];
        v = make_float4(a.x + b.x, a.y + b.y, a.z + b.z, a.w + b.w);
    } else {
        v = ((float4*)out)[idx];
    }
    const float inv = 1.0f / (Lbuf_g[0][row] + Lbuf_g[1][row]);
    v.x *= inv; v.y *= inv; v.z *= inv; v.w *= inv;
    ((float4*)out)[idx] = v;
}

extern "C" void kernel_launch(void* const* d_in, const int* in_sizes, int n_in,
                              void* d_out, int out_size, void* d_ws, size_t ws_size,
                              hipStream_t stream) {
    const float* x     = (const float*)d_in[0];
    const float* theta = (const float*)d_in[1];
    const float* W     = (const float*)d_in[2];
    const float* bias  = (const float*)d_in[3];
    float* out    = (float*)d_out;
    bf16_t* kperm = (bf16_t*)d_ws;                      // [4][128 tiles][32 frags][512] bf16
    bf16_t* qt    = kperm + (size_t)MTOT * EMBED;       // [4][512][4096] bf16
    bf16_t* abuf  = qt + (size_t)MTOT * EMBED;          // [16384][512] bf16
    float*  obuf  = (float*)(abuf + (size_t)MTOT * EMBED); // [2][16384][512] f32 (optional)

    const size_t need = (size_t)MTOT * EMBED * (2 + 2 + 2 + 8); // 3 bf16 bufs + 2 f32 partials
    const int split = (ws_size >= need) ? 1 : 0;

    if (!split)
        hipMemsetAsync(out, 0, (size_t)MTOT * EMBED * sizeof(float), stream);

    cvt_w_kernel<<<dim3(EMBED * EMBED / 4 / 256), dim3(256), 0, stream>>>(W);

    cvt_a_kernel<<<dim3(MTOT * EMBED / 8 / 256), dim3(256), 0, stream>>>(x, theta, abuf);

    gemm_q_kernel<<<dim3((MTOT / 128) * 4), dim3(256), 0, stream>>>(abuf, bias, kperm, qt);

    flash_kernel<<<dim3(64 * BATCH * NSPLIT), dim3(256), 0, stream>>>(kperm, qt, out, obuf, split);

    norm_kernel<<<dim3(MTOT * EMBED / 4 / 256), dim3(256), 0, stream>>>(out, obuf, split);
}

// Round 8
// 338.953 us; speedup vs baseline: 1.0122x; 1.0122x over previous
//
#include <hip/hip_runtime.h>

typedef __bf16 bf16_t;
typedef bf16_t bf16x8 __attribute__((ext_vector_type(8)));
typedef bf16_t bf16x4 __attribute__((ext_vector_type(4)));
typedef float f32x4 __attribute__((ext_vector_type(4)));

#define BATCH 4
#define SEQ 4096
#define EMBED 512
#define MTOT (BATCH * SEQ)
#define BC 32
#define FITERS (SEQ / BC)     // 128: full key range per block (no split)

__device__ bf16_t Wbf_g[EMBED * EMBED];  // W pre-converted to bf16

// async global->LDS, 16 B per lane; lds base must be wave-uniform
__device__ __forceinline__ void async_copy16(const bf16_t* g, bf16_t* l) {
    __builtin_amdgcn_global_load_lds(
        (const __attribute__((address_space(1))) unsigned int*)g,
        (__attribute__((address_space(3))) unsigned int*)l, 16, 0, 0);
}

// ---------------------------------------------------------------------------
// Stage 0a: W fp32 -> bf16 once.
// ---------------------------------------------------------------------------
__global__ __launch_bounds__(256) void cvt_w_kernel(const float* __restrict__ W) {
    const int i = (blockIdx.x * 256 + threadIdx.x) * 4;
    float4 v = *(const float4*)&W[i];
    bf16x4 o;
    o[0] = (bf16_t)v.x; o[1] = (bf16_t)v.y; o[2] = (bf16_t)v.z; o[3] = (bf16_t)v.w;
    *(bf16x4*)&Wbf_g[i] = o;
}

// ---------------------------------------------------------------------------
// Stage 0b: abuf = bf16(cos(x + theta)) — A operand precomputed once.
// ---------------------------------------------------------------------------
__global__ __launch_bounds__(256) void cvt_a_kernel(
    const float* __restrict__ x, const float* __restrict__ theta,
    bf16_t* __restrict__ abuf)
{
    const int i = (blockIdx.x * 256 + threadIdx.x) * 8;
    float4 a = *(const float4*)&x[i];
    float4 b = *(const float4*)&x[i + 4];
    const int e0 = i & 63;            // 8-aligned, no wrap within 8 elems
    bf16x8 o;
    o[0] = (bf16_t)__cosf(a.x + theta[e0 + 0]);
    o[1] = (bf16_t)__cosf(a.y + theta[e0 + 1]);
    o[2] = (bf16_t)__cosf(a.z + theta[e0 + 2]);
    o[3] = (bf16_t)__cosf(a.w + theta[e0 + 3]);
    o[4] = (bf16_t)__cosf(b.x + theta[e0 + 4]);
    o[5] = (bf16_t)__cosf(b.y + theta[e0 + 5]);
    o[6] = (bf16_t)__cosf(b.z + theta[e0 + 6]);
    o[7] = (bf16_t)__cosf(b.w + theta[e0 + 7]);
    *(bf16x8*)&abuf[i] = o;
}

// ---------------------------------------------------------------------------
// Stage 1: q = A @ W^T + b (M=16384, N=512, K=512), 128x128xBK64 MFMA GEMM,
// T2 both-sides swizzle, double-buffered staging, LDS-bounce epilogue
// (unchanged from R7). Writes kperm (MFMA-frag-major) + qt (e-major).
// ---------------------------------------------------------------------------
__global__ __launch_bounds__(256, 2) void gemm_q_kernel(
    const bf16_t* __restrict__ abuf, const float* __restrict__ bias,
    bf16_t* __restrict__ kperm, bf16_t* __restrict__ qt)
{
    __shared__ alignas(16) bf16_t smem[4 * 8192];  // 64 KB: [buf][As 16KB|Bs 16KB]

    const int t    = threadIdx.x;
    const int lane = t & 63;
    const int wave = t >> 6;
    const int l15  = lane & 15;
    const int quad = lane >> 4;
    const int m0   = (blockIdx.x >> 2) * 128;     // 128 m-tiles
    const int n0   = (blockIdx.x & 3) * 128;      // 4 n-tiles
    const int wm   = wave >> 1;                   // 0..1
    const int wn   = wave & 1;                    // 0..1

    const int drow = lane >> 3;                   // 0..7 (row within 8-row chunk)
    const int dseg = lane & 7;                    // 0..7 (16B segment)
    const int sseg = dseg ^ drow;                 // pre-swizzled source segment

    f32x4 acc[4][4];
#pragma unroll
    for (int mt = 0; mt < 4; ++mt)
#pragma unroll
        for (int nt = 0; nt < 4; ++nt) acc[mt][nt] = (f32x4){0.f, 0.f, 0.f, 0.f};

    auto stage = [&](int buf, int k0) {
        bf16_t* As = smem + buf * 16384;
        bf16_t* Bs = As + 8192;
#pragma unroll
        for (int j = 0; j < 4; ++j) {
            const int c   = wave * 4 + j;         // chunk 0..15 = rows c*8..c*8+7
            const int row = c * 8 + drow;
            async_copy16(&abuf[(size_t)(m0 + row) * 512 + k0 + sseg * 8], &As[c * 512]);
            async_copy16(&Wbf_g[(size_t)(n0 + row) * 512 + k0 + sseg * 8], &Bs[c * 512]);
        }
    };

    stage(0, 0);
    __syncthreads();            // DMA(0) landed
    int cur = 0;
    for (int kk = 0; kk < 8; ++kk) {
        if (kk + 1 < 8) stage(cur ^ 1, (kk + 1) * 64);   // prefetch next tile
        const bf16_t* As = smem + cur * 16384;
        const bf16_t* Bs = As + 8192;
#pragma unroll
        for (int kh = 0; kh < 2; ++kh) {
            bf16x8 af[4], bfr[4];
#pragma unroll
            for (int i = 0; i < 4; ++i) {
                const int rA = wm * 64 + i * 16 + l15;
                const int rB = wn * 64 + i * 16 + l15;
                const int sg = kh * 4 + quad;
                af[i]  = *(const bf16x8*)&As[rA * 64 + (sg ^ (rA & 7)) * 8];
                bfr[i] = *(const bf16x8*)&Bs[rB * 64 + (sg ^ (rB & 7)) * 8];
            }
#pragma unroll
            for (int mt = 0; mt < 4; ++mt)
#pragma unroll
                for (int nt = 0; nt < 4; ++nt)
                    acc[mt][nt] = __builtin_amdgcn_mfma_f32_16x16x32_bf16(af[mt], bfr[nt], acc[mt][nt], 0, 0, 0);
        }
        __syncthreads();        // drains prefetch DMA (covered by compute); frees cur
        cur ^= 1;
    }

    const int b     = m0 >> 12;          // batch
    const int mloc  = m0 & 4095;         // row base within batch (mult of 128)
    bf16_t* Es = smem;                   // 34 KB bounce, aliases staging bufs

    // ---- pass 1: kperm via LDS bounce ----
#pragma unroll
    for (int nt = 0; nt < 4; ++nt) {
        const int colL = wn * 64 + nt * 16 + l15;
        const float bv = bias[n0 + colL];
        const int kfL = colL >> 5;
        const int inc = ((colL >> 3) & 3) * 128 + (colL & 7);
#pragma unroll
        for (int mt = 0; mt < 4; ++mt) {
            const int rowL0 = wm * 64 + mt * 16 + quad * 4;
            const int c     = (rowL0 >> 5) * 8 + ((rowL0 >> 4) & 1) * 4 + kfL;
            const int base  = c * 512 + inc + (rowL0 & 15) * 8;
#pragma unroll
            for (int r = 0; r < 4; ++r)
                Es[base + r * 8] = (bf16_t)(acc[mt][nt][r] + bv);
        }
    }
    __syncthreads();
    {
        const int tileB = mloc >> 5;
        const int kfB   = n0 >> 5;
#pragma unroll
        for (int p = 0; p < 8; ++p) {
            const int flat = p * 256 + t;          // 0..2047
            const int c2   = flat >> 6;            // chunk 0..31
            const int off  = (flat & 63) * 8;
            const int tile = c2 >> 3;
            const int mh   = (c2 >> 2) & 1;
            const int kfL2 = c2 & 3;
            const size_t dst = (size_t)b * (SEQ * EMBED)
                             + (size_t)(tileB + tile) * 16384
                             + (size_t)(mh * 16 + kfB + kfL2) * 512 + off;
            *(bf16x8*)&kperm[dst] = *(const bf16x8*)&Es[c2 * 512 + off];
        }
    }
    __syncthreads();
    // ---- pass 2: qt via LDS transpose, Es as [colL][136] ----
#pragma unroll
    for (int nt = 0; nt < 4; ++nt) {
        const int colL = wn * 64 + nt * 16 + l15;
        const float bv = bias[n0 + colL];
#pragma unroll
        for (int mt = 0; mt < 4; ++mt) {
            const int rowL0 = wm * 64 + mt * 16 + quad * 4;
#pragma unroll
            for (int r = 0; r < 4; ++r)
                Es[colL * 136 + rowL0 + r] = (bf16_t)(acc[mt][nt][r] + bv);
        }
    }
    __syncthreads();
    {
#pragma unroll
        for (int p = 0; p < 8; ++p) {
            const int flat = p * 256 + t;          // 0..2047
            const int col  = flat >> 4;            // 0..127
            const int sub  = flat & 15;            // 8-row chunk
            *(bf16x8*)&qt[((size_t)(b * 512 + n0 + col) << 12) + mloc + sub * 8]
                = *(const bf16x8*)&Es[col * 136 + sub * 8];
        }
    }
}

// ---------------------------------------------------------------------------
// Stage 2: attention, NSPLIT=1. 512 thr / 8 waves, Br=64, Bc=32, grid 256
// (1 block/CU; same 2 waves/SIMD & same per-CU iter count as the old
// 2x256-thr config). Wave w: qg = w>>1 (16-q group), ktw = w&1 (16-key half)
// for QK; e-strip w*64 for PV. Full key range per block -> complete row
// sums -> in-kernel normalize, direct f32 out write. No obuf/Lbuf/norm.
// Same proven pipeline: 1 barrier/iter, V loads before K-DMA issue,
// setprio around PV cluster, frag-major Ks/Ps.
// ---------------------------------------------------------------------------
__global__ __launch_bounds__(512, 2) void flash_kernel(
    const bf16_t* __restrict__ kp, const bf16_t* __restrict__ qt,
    float* __restrict__ out)
{
    __shared__ alignas(16) bf16_t Ks[2][32 * 512];   // 64 KB, frag-major
    __shared__ alignas(16) bf16_t Ps[2][4 * 512];    //  8 KB, frag-major
    __shared__ float Ls[8][16];                      // per-wave row sums
    __shared__ float Lf[64];                         // 1/L per q-row

    const int t    = threadIdx.x;
    const int lane = t & 63;
    const int w    = t >> 6;        // 0..7
    const int l15  = lane & 15;
    const int quad = lane >> 4;
    const int qg   = w >> 1;        // 16-q group 0..3
    const int ktw  = w & 1;         // 16-key half 0..1

    // XCD remap: 256 blocks; each XCD's 32 blocks share one (batch, q-half)
    const int L      = blockIdx.x;          // 0..255
    const int xcd    = L & 7;
    const int slot   = L >> 3;              // 0..31
    const int batch  = xcd >> 1;            // 0..3
    const int qtile  = (xcd & 1) * 32 + slot;   // 0..63 (64-row q tiles)

    const int q0 = qtile * 64;
    const bf16_t* kpb = kp + (size_t)batch * SEQ * EMBED;
    const bf16_t* qtb = qt + (size_t)batch * EMBED * SEQ;

    // stage K-tile 0 (seq rows 0..31): 32 frags x 1 KB, 4 per wave
#pragma unroll
    for (int cc = 0; cc < 4; ++cc) {
        const int f = cc * 8 + w;
        async_copy16(&kpb[(size_t)f * 512 + lane * 8], &Ks[0][f * 512]);
    }

    // Q B-frags for q-rows q0+qg*16..+15 (kperm 32-row tile qtile*2+(qg>>1),
    // 16-row half qg&1)
    bf16x8 bQ[16];
    {
        const size_t qb = (size_t)(qtile * 2 + (qg >> 1)) * 16384
                        + (size_t)(qg & 1) * 16 * 512;
#pragma unroll
        for (int kf = 0; kf < 16; ++kf)
            bQ[kf] = *(const bf16x8*)&kpb[qb + kf * 512 + lane * 8];
    }

    f32x4 O[4][4];   // wave's PV: all 64 q x e-strip w*64 (4 n-tiles x 16)
#pragma unroll
    for (int m = 0; m < 4; ++m)
#pragma unroll
        for (int n = 0; n < 4; ++n) O[m][n] = (f32x4){0.f, 0.f, 0.f, 0.f};
    float lpart = 0.f;

    for (int it = 0; it < FITERS; ++it) {
        const int cbuf = it & 1;
        const int pbuf = cbuf ^ 1;
        __syncthreads();   // DMA K(it) landed; Ps(it-1) visible; Ks[pbuf] free
        // ---- V(it-1) global loads FIRST (older in vmcnt queue than DMA) ----
        bf16x8 bv[4];
        if (it) {
            const int kv = (it - 1) * BC;
#pragma unroll
            for (int n = 0; n < 4; ++n)
                bv[n] = *(const bf16x8*)&qtb[(size_t)(w * 64 + n * 16 + l15) * 4096
                                             + kv + quad * 8];
        }
        // ---- issue DMA K(it+1) into Ks[pbuf] (drains at next barrier) ----
        if (it + 1 < FITERS) {
#pragma unroll
            for (int cc = 0; cc < 4; ++cc) {
                const int f = cc * 8 + w;
                async_copy16(&kpb[(size_t)(it + 1) * 16384 + f * 512 + lane * 8],
                             &Ks[pbuf][f * 512]);
            }
        }
        // ---- QK(it): wave's 16x16 tile S^T = K[ktw] x Q[qg]^T, 2x8 chains ----
        f32x4 s;
        {
            f32x4 a0 = (f32x4){0.f, 0.f, 0.f, 0.f};
            f32x4 a1 = (f32x4){0.f, 0.f, 0.f, 0.f};
#pragma unroll
            for (int kf = 0; kf < 8; ++kf) {
                bf16x8 ak0 = *(const bf16x8*)&Ks[cbuf][(ktw * 16 + kf) * 512 + lane * 8];
                bf16x8 ak1 = *(const bf16x8*)&Ks[cbuf][(ktw * 16 + 8 + kf) * 512 + lane * 8];
                a0 = __builtin_amdgcn_mfma_f32_16x16x32_bf16(ak0, bQ[kf],     a0, 0, 0, 0);
                a1 = __builtin_amdgcn_mfma_f32_16x16x32_bf16(ak1, bQ[8 + kf], a1, 0, 0, 0);
            }
            s = a0 + a1;
        }
        // ---- P = exp(s/8): lane has P[key=ktw*16+quad*4+r][q=l15] ----
        {
            bf16x4 pk;
#pragma unroll
            for (int r = 0; r < 4; ++r) {
                bf16_t pb = (bf16_t)__expf(s[r] * 0.125f);
                lpart += (float)pb;
                pk[r] = pb;
            }
            // frag qg, elem (q=l15, k=ktw*16+quad*4+r):
            // off = (k>>3)*128 + l15*8 + (k&7)
            *(bf16x4*)&Ps[cbuf][qg * 512 + (ktw * 2 + (quad >> 1)) * 128
                                + l15 * 8 + (quad & 1) * 4] = pk;
        }
        // ---- PV(it-1): A=P frags (lane*16 seq reads), B=bv ----
        if (it) {
            bf16x8 pa[4];
#pragma unroll
            for (int mt = 0; mt < 4; ++mt)
                pa[mt] = *(const bf16x8*)&Ps[pbuf][mt * 512 + lane * 8];
            __builtin_amdgcn_s_setprio(1);
#pragma unroll
            for (int n = 0; n < 4; ++n)
#pragma unroll
                for (int mt = 0; mt < 4; ++mt)
                    O[mt][n] = __builtin_amdgcn_mfma_f32_16x16x32_bf16(pa[mt], bv[n], O[mt][n], 0, 0, 0);
            __builtin_amdgcn_s_setprio(0);
        }
    }
    // ---- final PV(FITERS-1) ----
    __syncthreads();
    {
        const int pbuf = (FITERS - 1) & 1;
        const int kv = (FITERS - 1) * BC;
        bf16x8 bv[4];
#pragma unroll
        for (int n = 0; n < 4; ++n)
            bv[n] = *(const bf16x8*)&qtb[(size_t)(w * 64 + n * 16 + l15) * 4096
                                         + kv + quad * 8];
        bf16x8 pa[4];
#pragma unroll
        for (int mt = 0; mt < 4; ++mt)
            pa[mt] = *(const bf16x8*)&Ps[pbuf][mt * 512 + lane * 8];
        __builtin_amdgcn_s_setprio(1);
#pragma unroll
        for (int n = 0; n < 4; ++n)
#pragma unroll
            for (int mt = 0; mt < 4; ++mt)
                O[mt][n] = __builtin_amdgcn_mfma_f32_16x16x32_bf16(pa[mt], bv[n], O[mt][n], 0, 0, 0);
        __builtin_amdgcn_s_setprio(0);
    }

    // ---- complete row sums -> 1/L in LDS ----
    {
        float ls = lpart;              // sum over this wave's quad-keys, all iters
        ls += __shfl_xor(ls, 16);
        ls += __shfl_xor(ls, 32);      // now sum over wave's 16 keys, per q=l15
        if (lane < 16) Ls[w][lane] = ls;
    }
    __syncthreads();
    if (t < 64)
        Lf[t] = 1.0f / (Ls[(t >> 4) * 2][t & 15] + Ls[(t >> 4) * 2 + 1][t & 15]);
    __syncthreads();

    // ---- normalized O -> out; D: row(q)=quad*4+r, col(e)=l15 ----
#pragma unroll
    for (int mt = 0; mt < 4; ++mt)
#pragma unroll
        for (int r = 0; r < 4; ++r) {
            const int qloc = mt * 16 + quad * 4 + r;
            const float inv = Lf[qloc];
            const size_t row = (size_t)batch * SEQ + q0 + qloc;
#pragma unroll
            for (int n = 0; n < 4; ++n)
                __builtin_nontemporal_store(O[mt][n][r] * inv,
                    &out[row * 512 + w * 64 + n * 16 + l15]);
        }
}

extern "C" void kernel_launch(void* const* d_in, const int* in_sizes, int n_in,
                              void* d_out, int out_size, void* d_ws, size_t ws_size,
                              hipStream_t stream) {
    const float* x     = (const float*)d_in[0];
    const float* theta = (const float*)d_in[1];
    const float* W     = (const float*)d_in[2];
    const float* bias  = (const float*)d_in[3];
    float* out    = (float*)d_out;
    bf16_t* kperm = (bf16_t*)d_ws;                      // [4][128 tiles][32 frags][512] bf16
    bf16_t* qt    = kperm + (size_t)MTOT * EMBED;       // [4][512][4096] bf16
    bf16_t* abuf  = qt + (size_t)MTOT * EMBED;          // [16384][512] bf16

    cvt_w_kernel<<<dim3(EMBED * EMBED / 4 / 256), dim3(256), 0, stream>>>(W);

    cvt_a_kernel<<<dim3(MTOT * EMBED / 8 / 256), dim3(256), 0, stream>>>(x, theta, abuf);

    gemm_q_kernel<<<dim3((MTOT / 128) * 4), dim3(256), 0, stream>>>(abuf, bias, kperm, qt);

    flash_kernel<<<dim3(SEQ / 64 * BATCH), dim3(512), 0, stream>>>(kperm, qt, out);
}